// Round 4
// baseline (132.676 us; speedup 1.0000x reference)
//
#include <hip/hip_runtime.h>
#include <math.h>

// DSA sparse attention, MI355X. B=2 H=8 S=2048 D=64 VD=64 T=128.
// fp32 in/out, int32 indices. One wave per query; 4 waves/block;
// blockIdx%16 = plane=(b*H+h) so blockIdx%8 pins each K/V plane to one XCD L2.
//
// R4 (latency-bound per R3 counters: VALUBusy 58%, Occ 54%, both pipes idle):
//  - ALL barriers and ALL LDS removed from the main kernel. Scores, indices
//    and indexer-scores live in registers; the cross-lane softmax and the
//    final output reduction use shfl_xor butterflies (lane bits 3..5).
//  - Works because phase1's row distribution (lane-group g handles rows
//    t = tc*8+g) is identical to phase3's, so each lane produces exactly the
//    16 (weight, idx) pairs it later consumes.
//  - idx/sc distributed by 2 coalesced loads + variable shfl (ds_bpermute).

#define BB 2
#define HH 8
#define SS 2048
#define DD 64
#define VDD 64
#define TT 128
#define SCALE 0.125f
#define NKV (BB * HH * SS * DD)          // 2097152 elements each for k and v

__device__ __forceinline__ float bf_lo(unsigned int u) {
    return __uint_as_float(u << 16);
}
// hi bf16 WITHOUT masking: low 16 junk bits are below bf16 rounding noise.
__device__ __forceinline__ float bf_hi(unsigned int u) {
    return __uint_as_float(u);
}
__device__ __forceinline__ unsigned short f2bf_rne(float f) {
    unsigned int u = __float_as_uint(f);
    u += 0x7FFFu + ((u >> 16) & 1u);     // round-to-nearest-even
    return (unsigned short)(u >> 16);
}

// ---- pre-pass: fp32 k,v -> bf16 kb,vb (packed 2/dword) ----
__global__ __launch_bounds__(256) void cvt_kv_bf16(
    const float* __restrict__ k, const float* __restrict__ v,
    unsigned int* __restrict__ kb, unsigned int* __restrict__ vb)
{
    int i = (blockIdx.x * 256 + threadIdx.x) * 4;   // 4 floats -> 2 dwords
    if (i >= NKV) return;
    float4 kf = *(const float4*)(k + i);
    float4 vf = *(const float4*)(v + i);
    unsigned int k0 = (unsigned int)f2bf_rne(kf.x) | ((unsigned int)f2bf_rne(kf.y) << 16);
    unsigned int k1 = (unsigned int)f2bf_rne(kf.z) | ((unsigned int)f2bf_rne(kf.w) << 16);
    unsigned int v0 = (unsigned int)f2bf_rne(vf.x) | ((unsigned int)f2bf_rne(vf.y) << 16);
    unsigned int v1 = (unsigned int)f2bf_rne(vf.z) | ((unsigned int)f2bf_rne(vf.w) << 16);
    *(uint2*)(kb + i / 2) = make_uint2(k0, k1);
    *(uint2*)(vb + i / 2) = make_uint2(v0, v1);
}

// ---- main: bf16 gather path, barrier-free, LDS-free ----
__global__ __launch_bounds__(256, 4) void dsa_sparse_attn_bf16(
    const float* __restrict__ q,
    const unsigned int* __restrict__ kb,   // bf16 pairs, row = 32 dwords
    const unsigned int* __restrict__ vb,
    const int* __restrict__ topk_idx,
    const float* __restrict__ topk_sc,
    float* __restrict__ out)
{
    const int tid  = threadIdx.x;
    const int wave = tid >> 6;
    const int lane = tid & 63;
    const int h    = lane & 7;           // dim-group: dwords h*4..h*4+3
    const int g    = lane >> 3;          // row-group: rows t = tc*8+g

    const int plane = blockIdx.x & 15;
    const int s     = (blockIdx.x >> 4) * 4 + wave;
    const int b     = plane >> 3;

    const float*        qp  = q  + ((size_t)plane * SS + s) * DD;
    const unsigned int* kp  = kb + (size_t)plane * SS * (DD / 2);
    const unsigned int* vp  = vb + (size_t)plane * SS * (VDD / 2);
    const int*          ip  = topk_idx + ((size_t)b * SS + s) * TT;
    const float*        scp = topk_sc  + ((size_t)b * SS + s) * TT;
    float*              op  = out + ((size_t)plane * SS + s) * VDD;

    // coalesced staging loads
    int   iv0 = ip[lane];
    int   iv1 = ip[64 + lane];
    float sv0 = scp[lane];
    float sv1 = scp[64 + lane];
    float4 qa = *(const float4*)(qp + h * 8);
    float4 qb = *(const float4*)(qp + h * 8 + 4);

    // distribute: lane (g,h) gets (idx, sc) for rows t = tc*8+g, tc=0..15
    int   idxr[16];
    float scr[16];
    #pragma unroll
    for (int tc = 0; tc < 16; ++tc) {
        int t = tc * 8 + g;
        if (tc < 8) { idxr[tc] = __shfl(iv0, t);      scr[tc] = __shfl(sv0, t); }
        else        { idxr[tc] = __shfl(iv1, t - 64); scr[tc] = __shfl(sv1, t - 64); }
    }

    // ---- phase 1: sco[tc] = scale * q . k[idx]; all lanes end with the dot ----
    float sco[16];
    #pragma unroll
    for (int tc = 0; tc < 16; ++tc) {
        uint4 kk = *(const uint4*)(kp + (size_t)idxr[tc] * 32 + h * 4);
        float acc;
        acc  = qa.x * bf_lo(kk.x) + qa.y * bf_hi(kk.x);
        acc += qa.z * bf_lo(kk.y) + qa.w * bf_hi(kk.y);
        acc += qb.x * bf_lo(kk.z) + qb.y * bf_hi(kk.z);
        acc += qb.z * bf_lo(kk.w) + qb.w * bf_hi(kk.w);
        acc += __shfl_xor(acc, 1);
        acc += __shfl_xor(acc, 2);
        acc += __shfl_xor(acc, 4);
        sco[tc] = acc * SCALE;
    }

    // ---- phase 2: register softmax * indexer score, renormalize ----
    float m = sco[0];
    #pragma unroll
    for (int tc = 1; tc < 16; ++tc) m = fmaxf(m, sco[tc]);
    m = fmaxf(m, __shfl_xor(m, 8));
    m = fmaxf(m, __shfl_xor(m, 16));
    m = fmaxf(m, __shfl_xor(m, 32));
    float sum = 0.f;
    #pragma unroll
    for (int tc = 0; tc < 16; ++tc) {
        float e = __expf(sco[tc] - m) * scr[tc];
        sco[tc] = e;
        sum += e;
    }
    sum += __shfl_xor(sum, 8);
    sum += __shfl_xor(sum, 16);
    sum += __shfl_xor(sum, 32);
    float inv = 1.0f / (sum + 1e-12f);

    // ---- phase 3: out[d] = sum_t w_t * v[idx_t][d]; weights already local ----
    float a[8] = {0.f, 0.f, 0.f, 0.f, 0.f, 0.f, 0.f, 0.f};
    #pragma unroll
    for (int tc = 0; tc < 16; ++tc) {
        float w = sco[tc] * inv;
        uint4 u = *(const uint4*)(vp + (size_t)idxr[tc] * 32 + h * 4);
        a[0] = fmaf(w, bf_lo(u.x), a[0]);  a[1] = fmaf(w, bf_hi(u.x), a[1]);
        a[2] = fmaf(w, bf_lo(u.y), a[2]);  a[3] = fmaf(w, bf_hi(u.y), a[3]);
        a[4] = fmaf(w, bf_lo(u.z), a[4]);  a[5] = fmaf(w, bf_hi(u.z), a[5]);
        a[6] = fmaf(w, bf_lo(u.w), a[6]);  a[7] = fmaf(w, bf_hi(u.w), a[7]);
    }
    #pragma unroll
    for (int j = 0; j < 8; ++j) {
        a[j] += __shfl_xor(a[j], 8);
        a[j] += __shfl_xor(a[j], 16);
        a[j] += __shfl_xor(a[j], 32);
    }
    if (g == 0) {
        *(float4*)(op + h * 8)     = make_float4(a[0], a[1], a[2], a[3]);
        *(float4*)(op + h * 8 + 4) = make_float4(a[4], a[5], a[6], a[7]);
    }
}

// ---- fallback fp32 kernel (used if ws too small) ----
__global__ __launch_bounds__(256, 4) void dsa_sparse_attn_f32(
    const float* __restrict__ q,
    const float* __restrict__ k,
    const float* __restrict__ v,
    const int* __restrict__ topk_idx,
    const float* __restrict__ topk_sc,
    float* __restrict__ out)
{
    const int tid  = threadIdx.x;
    const int wave = tid >> 6;
    const int lane = tid & 63;
    const int plane = blockIdx.x & 15;
    const int s     = (blockIdx.x >> 4) * 4 + wave;
    const int b     = plane >> 3;

    const float* qp  = q + ((size_t)plane * SS + s) * DD;
    const float* kp  = k + (size_t)plane * SS * DD;
    const float* vp  = v + (size_t)plane * SS * VDD;
    const int*   ip  = topk_idx + ((size_t)b * SS + s) * TT;
    const float* scp = topk_sc  + ((size_t)b * SS + s) * TT;
    float*       op  = out + ((size_t)plane * SS + s) * VDD;

    __shared__ int   s_idx[4][TT];
    __shared__ float s_w[4][TT];

    float sc0 = scp[lane];
    float sc1 = scp[64 + lane];
    s_idx[wave][lane]      = ip[lane];
    s_idx[wave][64 + lane] = ip[64 + lane];

    const int l = lane & 3;
    const int g = lane >> 2;
    float4 qf[4];
    #pragma unroll
    for (int j = 0; j < 4; ++j) qf[j] = *(const float4*)(qp + l * 4 + 16 * j);
    __syncthreads();

    #pragma unroll
    for (int tc = 0; tc < 8; ++tc) {
        int t = tc * 16 + g;
        const float* krow = kp + (size_t)s_idx[wave][t] * DD;
        float acc = 0.f;
        #pragma unroll
        for (int j = 0; j < 4; ++j) {
            float4 kf = *(const float4*)(krow + l * 4 + 16 * j);
            acc += qf[j].x * kf.x + qf[j].y * kf.y + qf[j].z * kf.z + qf[j].w * kf.w;
        }
        acc += __shfl_xor(acc, 1);
        acc += __shfl_xor(acc, 2);
        if (l == 0) s_w[wave][t] = acc * SCALE;
    }
    __syncthreads();

    float a0 = s_w[wave][lane];
    float a1 = s_w[wave][64 + lane];
    float m = fmaxf(a0, a1);
    #pragma unroll
    for (int off = 32; off >= 1; off >>= 1) m = fmaxf(m, __shfl_xor(m, off));
    float e0 = __expf(a0 - m) * sc0;
    float e1 = __expf(a1 - m) * sc1;
    float sum = e0 + e1;
    #pragma unroll
    for (int off = 32; off >= 1; off >>= 1) sum += __shfl_xor(sum, off);
    float inv = 1.0f / (sum + 1e-12f);
    s_w[wave][lane]      = e0 * inv;
    s_w[wave][64 + lane] = e1 * inv;
    __syncthreads();

    float acc = 0.f;
    #pragma unroll 8
    for (int t = 0; t < TT; ++t)
        acc = fmaf(s_w[wave][t], vp[(size_t)s_idx[wave][t] * VDD + lane], acc);
    op[lane] = acc;
}

extern "C" void kernel_launch(void* const* d_in, const int* in_sizes, int n_in,
                              void* d_out, int out_size, void* d_ws, size_t ws_size,
                              hipStream_t stream) {
    const float* q   = (const float*)d_in[0];
    const float* k   = (const float*)d_in[1];
    const float* v   = (const float*)d_in[2];
    const int*   idx = (const int*)d_in[3];
    const float* sc  = (const float*)d_in[4];
    float*       out = (float*)d_out;

    const size_t need = (size_t)NKV * 2 * 2;   // kb + vb, 2B each = 8.4 MB
    if (ws_size >= need) {
        unsigned int* kb = (unsigned int*)d_ws;
        unsigned int* vb = kb + NKV / 2;
        hipLaunchKernelGGL(cvt_kv_bf16, dim3(NKV / 4 / 256), dim3(256), 0, stream,
                           k, v, kb, vb);
        hipLaunchKernelGGL(dsa_sparse_attn_bf16, dim3(8192), dim3(256), 0, stream,
                           q, kb, vb, idx, sc, out);
    } else {
        hipLaunchKernelGGL(dsa_sparse_attn_f32, dim3(8192), dim3(256), 0, stream,
                           q, k, v, idx, sc, out);
    }
}

// Round 5
// 127.091 us; speedup vs baseline: 1.0439x; 1.0439x over previous
//
#include <hip/hip_runtime.h>
#include <math.h>

// DSA sparse attention, MI355X. B=2 H=8 S=2048 D=64 VD=64 T=128.
// fp32 in/out, int32 indices. One wave per query; 4 waves/block;
// blockIdx%16 = plane=(b*H+h) so blockIdx%8 pins each K/V plane to one XCD L2.
//
// R5 (spill-bound per R4 counters: WRITE_SIZE 8.2->25.5MB = scratch stores,
// occupancy 35%): barrier-free structure kept, but NO register arrays for
// idx/sc — they are re-fetched on demand with __shfl (ds_bpermute broadcast)
// from the two coalesced staging regs. Loops split into two 8-iter blocks
// (iv0 rows 0..63, iv1 rows 64..127) so SROA never sees conditional
// selection between the staging regs. SCALE folded into q.

#define BB 2
#define HH 8
#define SS 2048
#define DD 64
#define VDD 64
#define TT 128
#define SCALE 0.125f
#define NKV (BB * HH * SS * DD)          // 2097152 elements each for k and v

__device__ __forceinline__ float bf_lo(unsigned int u) {
    return __uint_as_float(u << 16);
}
// hi bf16 WITHOUT masking: low 16 junk bits are below bf16 rounding noise.
__device__ __forceinline__ float bf_hi(unsigned int u) {
    return __uint_as_float(u);
}
__device__ __forceinline__ unsigned short f2bf_rne(float f) {
    unsigned int u = __float_as_uint(f);
    u += 0x7FFFu + ((u >> 16) & 1u);     // round-to-nearest-even
    return (unsigned short)(u >> 16);
}

// ---- pre-pass: fp32 k,v -> bf16 kb,vb (packed 2/dword) ----
__global__ __launch_bounds__(256) void cvt_kv_bf16(
    const float* __restrict__ k, const float* __restrict__ v,
    unsigned int* __restrict__ kb, unsigned int* __restrict__ vb)
{
    int i = (blockIdx.x * 256 + threadIdx.x) * 4;   // 4 floats -> 2 dwords
    if (i >= NKV) return;
    float4 kf = *(const float4*)(k + i);
    float4 vf = *(const float4*)(v + i);
    unsigned int k0 = (unsigned int)f2bf_rne(kf.x) | ((unsigned int)f2bf_rne(kf.y) << 16);
    unsigned int k1 = (unsigned int)f2bf_rne(kf.z) | ((unsigned int)f2bf_rne(kf.w) << 16);
    unsigned int v0 = (unsigned int)f2bf_rne(vf.x) | ((unsigned int)f2bf_rne(vf.y) << 16);
    unsigned int v1 = (unsigned int)f2bf_rne(vf.z) | ((unsigned int)f2bf_rne(vf.w) << 16);
    *(uint2*)(kb + i / 2) = make_uint2(k0, k1);
    *(uint2*)(vb + i / 2) = make_uint2(v0, v1);
}

// ---- main: bf16 gather path, barrier-free, LDS-free, array-free ----
__global__ __launch_bounds__(256, 4) void dsa_sparse_attn_bf16(
    const float* __restrict__ q,
    const unsigned int* __restrict__ kb,   // bf16 pairs, row = 32 dwords
    const unsigned int* __restrict__ vb,
    const int* __restrict__ topk_idx,
    const float* __restrict__ topk_sc,
    float* __restrict__ out)
{
    const int tid  = threadIdx.x;
    const int wave = tid >> 6;
    const int lane = tid & 63;
    const int h    = lane & 7;           // dim-group: dwords h*4..h*4+3
    const int g    = lane >> 3;          // row-group: rows t = tc*8+g

    const int plane = blockIdx.x & 15;
    const int s     = (blockIdx.x >> 4) * 4 + wave;
    const int b     = plane >> 3;

    const float*        qp  = q  + ((size_t)plane * SS + s) * DD;
    const unsigned int* kp  = kb + (size_t)plane * SS * (DD / 2);
    const unsigned int* vp  = vb + (size_t)plane * SS * (VDD / 2);
    const int*          ip  = topk_idx + ((size_t)b * SS + s) * TT;
    const float*        scp = topk_sc  + ((size_t)b * SS + s) * TT;
    float*              op  = out + ((size_t)plane * SS + s) * VDD;

    // coalesced staging loads (these 4 regs are the only persistent copies)
    int   iv0 = ip[lane];
    int   iv1 = ip[64 + lane];
    float sv0 = scp[lane];
    float sv1 = scp[64 + lane];
    float4 qa = *(const float4*)(qp + h * 8);
    float4 qb = *(const float4*)(qp + h * 8 + 4);
    qa.x *= SCALE; qa.y *= SCALE; qa.z *= SCALE; qa.w *= SCALE;
    qb.x *= SCALE; qb.y *= SCALE; qb.z *= SCALE; qb.w *= SCALE;

    // ---- phase 1: sco[tc] = q . k[idx_t] (scale pre-folded) ----
    float sco[16];
    #pragma unroll
    for (int tc = 0; tc < 8; ++tc) {
        int idx = __shfl(iv0, tc * 8 + g);
        uint4 kk = *(const uint4*)(kp + (size_t)idx * 32 + h * 4);
        float acc;
        acc  = qa.x * bf_lo(kk.x) + qa.y * bf_hi(kk.x);
        acc += qa.z * bf_lo(kk.y) + qa.w * bf_hi(kk.y);
        acc += qb.x * bf_lo(kk.z) + qb.y * bf_hi(kk.z);
        acc += qb.z * bf_lo(kk.w) + qb.w * bf_hi(kk.w);
        acc += __shfl_xor(acc, 1);
        acc += __shfl_xor(acc, 2);
        acc += __shfl_xor(acc, 4);
        sco[tc] = acc;
    }
    #pragma unroll
    for (int tc = 0; tc < 8; ++tc) {
        int idx = __shfl(iv1, tc * 8 + g);
        uint4 kk = *(const uint4*)(kp + (size_t)idx * 32 + h * 4);
        float acc;
        acc  = qa.x * bf_lo(kk.x) + qa.y * bf_hi(kk.x);
        acc += qa.z * bf_lo(kk.y) + qa.w * bf_hi(kk.y);
        acc += qb.x * bf_lo(kk.z) + qb.y * bf_hi(kk.z);
        acc += qb.z * bf_lo(kk.w) + qb.w * bf_hi(kk.w);
        acc += __shfl_xor(acc, 1);
        acc += __shfl_xor(acc, 2);
        acc += __shfl_xor(acc, 4);
        sco[8 + tc] = acc;
    }

    // ---- phase 2: register softmax * indexer score, renormalize ----
    float m = sco[0];
    #pragma unroll
    for (int tc = 1; tc < 16; ++tc) m = fmaxf(m, sco[tc]);
    m = fmaxf(m, __shfl_xor(m, 8));
    m = fmaxf(m, __shfl_xor(m, 16));
    m = fmaxf(m, __shfl_xor(m, 32));
    float sum = 0.f;
    #pragma unroll
    for (int tc = 0; tc < 8; ++tc) {
        float e = __expf(sco[tc] - m) * __shfl(sv0, tc * 8 + g);
        sco[tc] = e;
        sum += e;
    }
    #pragma unroll
    for (int tc = 0; tc < 8; ++tc) {
        float e = __expf(sco[8 + tc] - m) * __shfl(sv1, tc * 8 + g);
        sco[8 + tc] = e;
        sum += e;
    }
    sum += __shfl_xor(sum, 8);
    sum += __shfl_xor(sum, 16);
    sum += __shfl_xor(sum, 32);
    float inv = 1.0f / (sum + 1e-12f);

    // ---- phase 3: out[d] = sum_t w_t * v[idx_t][d] ----
    float a[8] = {0.f, 0.f, 0.f, 0.f, 0.f, 0.f, 0.f, 0.f};
    #pragma unroll
    for (int tc = 0; tc < 8; ++tc) {
        int   idx = __shfl(iv0, tc * 8 + g);
        float w   = sco[tc] * inv;
        uint4 u = *(const uint4*)(vp + (size_t)idx * 32 + h * 4);
        a[0] = fmaf(w, bf_lo(u.x), a[0]);  a[1] = fmaf(w, bf_hi(u.x), a[1]);
        a[2] = fmaf(w, bf_lo(u.y), a[2]);  a[3] = fmaf(w, bf_hi(u.y), a[3]);
        a[4] = fmaf(w, bf_lo(u.z), a[4]);  a[5] = fmaf(w, bf_hi(u.z), a[5]);
        a[6] = fmaf(w, bf_lo(u.w), a[6]);  a[7] = fmaf(w, bf_hi(u.w), a[7]);
    }
    #pragma unroll
    for (int tc = 0; tc < 8; ++tc) {
        int   idx = __shfl(iv1, tc * 8 + g);
        float w   = sco[8 + tc] * inv;
        uint4 u = *(const uint4*)(vp + (size_t)idx * 32 + h * 4);
        a[0] = fmaf(w, bf_lo(u.x), a[0]);  a[1] = fmaf(w, bf_hi(u.x), a[1]);
        a[2] = fmaf(w, bf_lo(u.y), a[2]);  a[3] = fmaf(w, bf_hi(u.y), a[3]);
        a[4] = fmaf(w, bf_lo(u.z), a[4]);  a[5] = fmaf(w, bf_hi(u.z), a[5]);
        a[6] = fmaf(w, bf_lo(u.w), a[6]);  a[7] = fmaf(w, bf_hi(u.w), a[7]);
    }
    #pragma unroll
    for (int j = 0; j < 8; ++j) {
        a[j] += __shfl_xor(a[j], 8);
        a[j] += __shfl_xor(a[j], 16);
        a[j] += __shfl_xor(a[j], 32);
    }
    if (g == 0) {
        *(float4*)(op + h * 8)     = make_float4(a[0], a[1], a[2], a[3]);
        *(float4*)(op + h * 8 + 4) = make_float4(a[4], a[5], a[6], a[7]);
    }
}

// ---- fallback fp32 kernel (used if ws too small) ----
__global__ __launch_bounds__(256, 4) void dsa_sparse_attn_f32(
    const float* __restrict__ q,
    const float* __restrict__ k,
    const float* __restrict__ v,
    const int* __restrict__ topk_idx,
    const float* __restrict__ topk_sc,
    float* __restrict__ out)
{
    const int tid  = threadIdx.x;
    const int wave = tid >> 6;
    const int lane = tid & 63;
    const int plane = blockIdx.x & 15;
    const int s     = (blockIdx.x >> 4) * 4 + wave;
    const int b     = plane >> 3;

    const float* qp  = q + ((size_t)plane * SS + s) * DD;
    const float* kp  = k + (size_t)plane * SS * DD;
    const float* vp  = v + (size_t)plane * SS * VDD;
    const int*   ip  = topk_idx + ((size_t)b * SS + s) * TT;
    const float* scp = topk_sc  + ((size_t)b * SS + s) * TT;
    float*       op  = out + ((size_t)plane * SS + s) * VDD;

    __shared__ int   s_idx[4][TT];
    __shared__ float s_w[4][TT];

    float sc0 = scp[lane];
    float sc1 = scp[64 + lane];
    s_idx[wave][lane]      = ip[lane];
    s_idx[wave][64 + lane] = ip[64 + lane];

    const int l = lane & 3;
    const int g = lane >> 2;
    float4 qf[4];
    #pragma unroll
    for (int j = 0; j < 4; ++j) qf[j] = *(const float4*)(qp + l * 4 + 16 * j);
    __syncthreads();

    #pragma unroll
    for (int tc = 0; tc < 8; ++tc) {
        int t = tc * 16 + g;
        const float* krow = kp + (size_t)s_idx[wave][t] * DD;
        float acc = 0.f;
        #pragma unroll
        for (int j = 0; j < 4; ++j) {
            float4 kf = *(const float4*)(krow + l * 4 + 16 * j);
            acc += qf[j].x * kf.x + qf[j].y * kf.y + qf[j].z * kf.z + qf[j].w * kf.w;
        }
        acc += __shfl_xor(acc, 1);
        acc += __shfl_xor(acc, 2);
        if (l == 0) s_w[wave][t] = acc * SCALE;
    }
    __syncthreads();

    float a0 = s_w[wave][lane];
    float a1 = s_w[wave][64 + lane];
    float m = fmaxf(a0, a1);
    #pragma unroll
    for (int off = 32; off >= 1; off >>= 1) m = fmaxf(m, __shfl_xor(m, off));
    float e0 = __expf(a0 - m) * sc0;
    float e1 = __expf(a1 - m) * sc1;
    float sum = e0 + e1;
    #pragma unroll
    for (int off = 32; off >= 1; off >>= 1) sum += __shfl_xor(sum, off);
    float inv = 1.0f / (sum + 1e-12f);
    s_w[wave][lane]      = e0 * inv;
    s_w[wave][64 + lane] = e1 * inv;
    __syncthreads();

    float acc = 0.f;
    #pragma unroll 8
    for (int t = 0; t < TT; ++t)
        acc = fmaf(s_w[wave][t], vp[(size_t)s_idx[wave][t] * VDD + lane], acc);
    op[lane] = acc;
}

extern "C" void kernel_launch(void* const* d_in, const int* in_sizes, int n_in,
                              void* d_out, int out_size, void* d_ws, size_t ws_size,
                              hipStream_t stream) {
    const float* q   = (const float*)d_in[0];
    const float* k   = (const float*)d_in[1];
    const float* v   = (const float*)d_in[2];
    const int*   idx = (const int*)d_in[3];
    const float* sc  = (const float*)d_in[4];
    float*       out = (float*)d_out;

    const size_t need = (size_t)NKV * 2 * 2;   // kb + vb, 2B each = 8.4 MB
    if (ws_size >= need) {
        unsigned int* kb = (unsigned int*)d_ws;
        unsigned int* vb = kb + NKV / 2;
        hipLaunchKernelGGL(cvt_kv_bf16, dim3(NKV / 4 / 256), dim3(256), 0, stream,
                           k, v, kb, vb);
        hipLaunchKernelGGL(dsa_sparse_attn_bf16, dim3(8192), dim3(256), 0, stream,
                           q, kb, vb, idx, sc, out);
    } else {
        hipLaunchKernelGGL(dsa_sparse_attn_f32, dim3(8192), dim3(256), 0, stream,
                           q, k, v, idx, sc, out);
    }
}

// Round 7
// 125.059 us; speedup vs baseline: 1.0609x; 1.0162x over previous
//
#include <hip/hip_runtime.h>
#include <math.h>

// DSA sparse attention, MI355X. B=2 H=8 S=2048 D=64 VD=64 T=128.
// fp32 in/out, int32 indices. One wave per query; 4 waves/block;
// blockIdx%16 = plane=(b*H+h) so blockIdx%8 pins each K/V plane to one XCD L2.
//
// R7 = R6 with the type fix: __builtin_amdgcn_cvt_pkrtz / fdot2 use
// __fp16-based ext vectors (clang's return/param type), not _Float16.
//  - K stored as f16, phase1 dot via v_dot2_f32_f16: 4 dot2/row.
//  - V stays bf16; phase3 accumulates in packed float2 (v_pk_fma_f32).
//  - Deferred normalization: exp*indexer folded into phase3 loop, cross-lane
//    sum AFTER the loop, single inv scale at the end.

#define BB 2
#define HH 8
#define SS 2048
#define DD 64
#define VDD 64
#define TT 128
#define SCALE 0.125f
#define NKV (BB * HH * SS * DD)          // 2097152 elements each for k and v

typedef __fp16 h2 __attribute__((ext_vector_type(2)));   // builtin interop type
typedef float  f2 __attribute__((ext_vector_type(2)));

__device__ __forceinline__ float bf_lo(unsigned int u) {
    return __uint_as_float(u << 16);
}
// hi bf16 WITHOUT masking: low 16 junk bits are below bf16 rounding noise.
__device__ __forceinline__ float bf_hi(unsigned int u) {
    return __uint_as_float(u);
}
__device__ __forceinline__ unsigned short f2bf_rne(float f) {
    unsigned int u = __float_as_uint(f);
    u += 0x7FFFu + ((u >> 16) & 1u);     // round-to-nearest-even
    return (unsigned short)(u >> 16);
}
__device__ __forceinline__ unsigned int pk_f16(float x, float y) {
    h2 p = __builtin_amdgcn_cvt_pkrtz(x, y);
    return __builtin_bit_cast(unsigned int, p);
}
__device__ __forceinline__ float dot2(unsigned int qh, unsigned int kh, float c) {
    return __builtin_amdgcn_fdot2(__builtin_bit_cast(h2, qh),
                                  __builtin_bit_cast(h2, kh), c, false);
}

// ---- pre-pass: fp32 k -> f16 kh; fp32 v -> bf16 vb (packed 2/dword) ----
__global__ __launch_bounds__(256) void cvt_kv(
    const float* __restrict__ k, const float* __restrict__ v,
    unsigned int* __restrict__ kh, unsigned int* __restrict__ vb)
{
    int i = (blockIdx.x * 256 + threadIdx.x) * 4;   // 4 floats -> 2 dwords
    if (i >= NKV) return;
    float4 kf = *(const float4*)(k + i);
    float4 vf = *(const float4*)(v + i);
    unsigned int k0 = pk_f16(kf.x, kf.y);
    unsigned int k1 = pk_f16(kf.z, kf.w);
    unsigned int v0 = (unsigned int)f2bf_rne(vf.x) | ((unsigned int)f2bf_rne(vf.y) << 16);
    unsigned int v1 = (unsigned int)f2bf_rne(vf.z) | ((unsigned int)f2bf_rne(vf.w) << 16);
    *(uint2*)(kh + i / 2) = make_uint2(k0, k1);
    *(uint2*)(vb + i / 2) = make_uint2(v0, v1);
}

// ---- main: f16-K / bf16-V gather path, barrier-free, LDS-free ----
__global__ __launch_bounds__(256, 4) void dsa_sparse_attn_bf16(
    const float* __restrict__ q,
    const unsigned int* __restrict__ kh,   // f16 pairs, row = 32 dwords
    const unsigned int* __restrict__ vb,   // bf16 pairs, row = 32 dwords
    const int* __restrict__ topk_idx,
    const float* __restrict__ topk_sc,
    float* __restrict__ out)
{
    const int tid  = threadIdx.x;
    const int wave = tid >> 6;
    const int lane = tid & 63;
    const int h    = lane & 7;           // dim-group: dwords h*4..h*4+3
    const int g    = lane >> 3;          // row-group: rows t = tc*8+g

    const int plane = blockIdx.x & 15;
    const int s     = (blockIdx.x >> 4) * 4 + wave;
    const int b     = plane >> 3;

    const float*        qp  = q  + ((size_t)plane * SS + s) * DD;
    const unsigned int* kp  = kh + (size_t)plane * SS * (DD / 2);
    const unsigned int* vp  = vb + (size_t)plane * SS * (VDD / 2);
    const int*          ip  = topk_idx + ((size_t)b * SS + s) * TT;
    const float*        scp = topk_sc  + ((size_t)b * SS + s) * TT;
    float*              op  = out + ((size_t)plane * SS + s) * VDD;

    // coalesced staging loads
    int   iv0 = ip[lane];
    int   iv1 = ip[64 + lane];
    float sv0 = scp[lane];
    float sv1 = scp[64 + lane];
    float4 qa = *(const float4*)(qp + h * 8);
    float4 qb = *(const float4*)(qp + h * 8 + 4);
    // scale folded into q, then packed to f16 pairs matching k's dword layout
    unsigned int q0 = pk_f16(qa.x * SCALE, qa.y * SCALE);
    unsigned int q1 = pk_f16(qa.z * SCALE, qa.w * SCALE);
    unsigned int q2 = pk_f16(qb.x * SCALE, qb.y * SCALE);
    unsigned int q3 = pk_f16(qb.z * SCALE, qb.w * SCALE);

    // ---- phase 1: sco[tc] = q . k[idx_t] via v_dot2_f32_f16 ----
    float sco[16];
    #pragma unroll
    for (int tc = 0; tc < 8; ++tc) {
        int idx = __shfl(iv0, tc * 8 + g);
        uint4 kk = *(const uint4*)(kp + (size_t)idx * 32 + h * 4);
        float acc = dot2(q0, kk.x, dot2(q1, kk.y, dot2(q2, kk.z, dot2(q3, kk.w, 0.f))));
        acc += __shfl_xor(acc, 1);
        acc += __shfl_xor(acc, 2);
        acc += __shfl_xor(acc, 4);
        sco[tc] = acc;
    }
    #pragma unroll
    for (int tc = 0; tc < 8; ++tc) {
        int idx = __shfl(iv1, tc * 8 + g);
        uint4 kk = *(const uint4*)(kp + (size_t)idx * 32 + h * 4);
        float acc = dot2(q0, kk.x, dot2(q1, kk.y, dot2(q2, kk.z, dot2(q3, kk.w, 0.f))));
        acc += __shfl_xor(acc, 1);
        acc += __shfl_xor(acc, 2);
        acc += __shfl_xor(acc, 4);
        sco[8 + tc] = acc;
    }

    // ---- phase 2 (max only; sum is deferred past the V loop) ----
    float m = sco[0];
    #pragma unroll
    for (int tc = 1; tc < 16; ++tc) m = fmaxf(m, sco[tc]);
    m = fmaxf(m, __shfl_xor(m, 8));
    m = fmaxf(m, __shfl_xor(m, 16));
    m = fmaxf(m, __shfl_xor(m, 32));

    // ---- phase 3: unnormalized acc += e_t * v[idx_t]; packed float2 math ----
    f2 a0 = {0.f, 0.f}, a1 = {0.f, 0.f}, a2 = {0.f, 0.f}, a3 = {0.f, 0.f};
    float sum = 0.f;
    #pragma unroll
    for (int tc = 0; tc < 8; ++tc) {
        int   idx = __shfl(iv0, tc * 8 + g);
        uint4 u   = *(const uint4*)(vp + (size_t)idx * 32 + h * 4);
        float e   = __expf(sco[tc] - m) * __shfl(sv0, tc * 8 + g);
        sum += e;
        f2 wv = {e, e};
        f2 vx = {bf_lo(u.x), bf_hi(u.x)};
        f2 vy = {bf_lo(u.y), bf_hi(u.y)};
        f2 vz = {bf_lo(u.z), bf_hi(u.z)};
        f2 vw = {bf_lo(u.w), bf_hi(u.w)};
        a0 = __builtin_elementwise_fma(wv, vx, a0);
        a1 = __builtin_elementwise_fma(wv, vy, a1);
        a2 = __builtin_elementwise_fma(wv, vz, a2);
        a3 = __builtin_elementwise_fma(wv, vw, a3);
    }
    #pragma unroll
    for (int tc = 0; tc < 8; ++tc) {
        int   idx = __shfl(iv1, tc * 8 + g);
        uint4 u   = *(const uint4*)(vp + (size_t)idx * 32 + h * 4);
        float e   = __expf(sco[8 + tc] - m) * __shfl(sv1, tc * 8 + g);
        sum += e;
        f2 wv = {e, e};
        f2 vx = {bf_lo(u.x), bf_hi(u.x)};
        f2 vy = {bf_lo(u.y), bf_hi(u.y)};
        f2 vz = {bf_lo(u.z), bf_hi(u.z)};
        f2 vw = {bf_lo(u.w), bf_hi(u.w)};
        a0 = __builtin_elementwise_fma(wv, vx, a0);
        a1 = __builtin_elementwise_fma(wv, vy, a1);
        a2 = __builtin_elementwise_fma(wv, vz, a2);
        a3 = __builtin_elementwise_fma(wv, vw, a3);
    }

    // cross-lane: weight-sum, then 8 output partials over row-groups (bits 3..5)
    sum += __shfl_xor(sum, 8);
    sum += __shfl_xor(sum, 16);
    sum += __shfl_xor(sum, 32);

    float a[8] = {a0.x, a0.y, a1.x, a1.y, a2.x, a2.y, a3.x, a3.y};
    #pragma unroll
    for (int j = 0; j < 8; ++j) {
        a[j] += __shfl_xor(a[j], 8);
        a[j] += __shfl_xor(a[j], 16);
        a[j] += __shfl_xor(a[j], 32);
    }
    if (g == 0) {
        float inv = 1.0f / (sum + 1e-12f);
        *(float4*)(op + h * 8)     = make_float4(a[0] * inv, a[1] * inv, a[2] * inv, a[3] * inv);
        *(float4*)(op + h * 8 + 4) = make_float4(a[4] * inv, a[5] * inv, a[6] * inv, a[7] * inv);
    }
}

// ---- fallback fp32 kernel (used if ws too small) ----
__global__ __launch_bounds__(256, 4) void dsa_sparse_attn_f32(
    const float* __restrict__ q,
    const float* __restrict__ k,
    const float* __restrict__ v,
    const int* __restrict__ topk_idx,
    const float* __restrict__ topk_sc,
    float* __restrict__ out)
{
    const int tid  = threadIdx.x;
    const int wave = tid >> 6;
    const int lane = tid & 63;
    const int plane = blockIdx.x & 15;
    const int s     = (blockIdx.x >> 4) * 4 + wave;
    const int b     = plane >> 3;

    const float* qp  = q + ((size_t)plane * SS + s) * DD;
    const float* kp  = k + (size_t)plane * SS * DD;
    const float* vp  = v + (size_t)plane * SS * VDD;
    const int*   ip  = topk_idx + ((size_t)b * SS + s) * TT;
    const float* scp = topk_sc  + ((size_t)b * SS + s) * TT;
    float*       op  = out + ((size_t)plane * SS + s) * VDD;

    __shared__ int   s_idx[4][TT];
    __shared__ float s_w[4][TT];

    float sc0 = scp[lane];
    float sc1 = scp[64 + lane];
    s_idx[wave][lane]      = ip[lane];
    s_idx[wave][64 + lane] = ip[64 + lane];

    const int l = lane & 3;
    const int g = lane >> 2;
    float4 qf[4];
    #pragma unroll
    for (int j = 0; j < 4; ++j) qf[j] = *(const float4*)(qp + l * 4 + 16 * j);
    __syncthreads();

    #pragma unroll
    for (int tc = 0; tc < 8; ++tc) {
        int t = tc * 16 + g;
        const float* krow = kp + (size_t)s_idx[wave][t] * DD;
        float acc = 0.f;
        #pragma unroll
        for (int j = 0; j < 4; ++j) {
            float4 kf = *(const float4*)(krow + l * 4 + 16 * j);
            acc += qf[j].x * kf.x + qf[j].y * kf.y + qf[j].z * kf.z + qf[j].w * kf.w;
        }
        acc += __shfl_xor(acc, 1);
        acc += __shfl_xor(acc, 2);
        if (l == 0) s_w[wave][t] = acc * SCALE;
    }
    __syncthreads();

    float a0 = s_w[wave][lane];
    float a1 = s_w[wave][64 + lane];
    float m = fmaxf(a0, a1);
    #pragma unroll
    for (int off = 32; off >= 1; off >>= 1) m = fmaxf(m, __shfl_xor(m, off));
    float e0 = __expf(a0 - m) * sc0;
    float e1 = __expf(a1 - m) * sc1;
    float sum = e0 + e1;
    #pragma unroll
    for (int off = 32; off >= 1; off >>= 1) sum += __shfl_xor(sum, off);
    float inv = 1.0f / (sum + 1e-12f);
    s_w[wave][lane]      = e0 * inv;
    s_w[wave][64 + lane] = e1 * inv;
    __syncthreads();

    float acc = 0.f;
    #pragma unroll 8
    for (int t = 0; t < TT; ++t)
        acc = fmaf(s_w[wave][t], vp[(size_t)s_idx[wave][t] * VDD + lane], acc);
    op[lane] = acc;
}

extern "C" void kernel_launch(void* const* d_in, const int* in_sizes, int n_in,
                              void* d_out, int out_size, void* d_ws, size_t ws_size,
                              hipStream_t stream) {
    const float* q   = (const float*)d_in[0];
    const float* k   = (const float*)d_in[1];
    const float* v   = (const float*)d_in[2];
    const int*   idx = (const int*)d_in[3];
    const float* sc  = (const float*)d_in[4];
    float*       out = (float*)d_out;

    const size_t need = (size_t)NKV * 2 * 2;   // kh + vb, 2B each = 8.4 MB
    if (ws_size >= need) {
        unsigned int* kh = (unsigned int*)d_ws;
        unsigned int* vb = kh + NKV / 2;
        hipLaunchKernelGGL(cvt_kv, dim3(NKV / 4 / 256), dim3(256), 0, stream,
                           k, v, kh, vb);
        hipLaunchKernelGGL(dsa_sparse_attn_bf16, dim3(8192), dim3(256), 0, stream,
                           q, kh, vb, idx, sc, out);
    } else {
        hipLaunchKernelGGL(dsa_sparse_attn_f32, dim3(8192), dim3(256), 0, stream,
                           q, k, v, idx, sc, out);
    }
}